// Round 7
// baseline (2172.865 us; speedup 1.0000x reference)
//
#include <hip/hip_runtime.h>
#include <hip/hip_cooperative_groups.h>

#define BB 64      // batch
#define TT 256     // time
#define EE 256     // embed dim
#define NU 1024    // hidden units
#define N3 3072    // 3*NU

typedef __attribute__((ext_vector_type(8))) short bf16x8;
typedef __attribute__((ext_vector_type(4))) float f32x4;

__device__ __forceinline__ unsigned short f2bf(float f) {
    unsigned u = __float_as_uint(f);
    return (unsigned short)((u + 0x7FFFu + ((u >> 16) & 1u)) >> 16);
}

// ---------------------------------------------------------------------------
// Kernel 0a: pack U[k][g*NU+u] -> Upack[u*3+g][k]  (fp32, unchanged)
// ---------------------------------------------------------------------------
__global__ __launch_bounds__(256) void upack_kernel(
    const float* __restrict__ U, float* __restrict__ up)
{
    __shared__ float t32[32][33];
    const int c0 = blockIdx.x * 32, k0 = blockIdx.y * 32;
    const int tx = threadIdx.x & 31, ty = threadIdx.x >> 5;
    #pragma unroll
    for (int i = 0; i < 4; ++i) {
        int k = ty + i * 8;
        t32[k][tx] = U[(size_t)(k0 + k) * N3 + c0 + tx];
    }
    __syncthreads();
    #pragma unroll
    for (int i = 0; i < 4; ++i) {
        int cl = ty + i * 8;
        int c = c0 + cl;
        int u = c & 1023, g = c >> 10;
        up[(size_t)(u * 3 + g) * NU + k0 + tx] = t32[tx][cl];
    }
}

// ---------------------------------------------------------------------------
// Kernel 0b: transpose tokens; 0c: init h_bf16 (frag layout) + zero counters
// h_bf layout: elem((k,b)) = ((k>>3)*64 + b)*8 + (k&7)
// ---------------------------------------------------------------------------
__global__ __launch_bounds__(64) void tokT_kernel(
    const int* __restrict__ x, int* __restrict__ xT)
{
    const int t = blockIdx.x, b = threadIdx.x;
    xT[t * BB + b] = x[b * TT + t];
}

__global__ __launch_bounds__(256) void hinit_kernel(
    const float* __restrict__ hidden, unsigned short* __restrict__ hb0,
    unsigned* __restrict__ cnt)
{
    const int u = blockIdx.x * 4 + (threadIdx.x >> 6);
    const int b = threadIdx.x & 63;
    hb0[((u >> 3) * 64 + b) * 8 + (u & 7)] = f2bf(hidden[(size_t)b * NU + u]);
    if (blockIdx.x == 0) {
        cnt[threadIdx.x] = 0u;           // 8 group counters, 128B apart
        cnt[threadIdx.x + 256] = 0u;
    }
}

// ---------------------------------------------------------------------------
// Kernel 1: xprojT[t][c][b] = (emb[x[b,t]] @ W + b0)[c]   (unchanged)
// ---------------------------------------------------------------------------
__global__ __launch_bounds__(256) void xprojT_kernel(
    const int* __restrict__ x, const float* __restrict__ emb,
    const float* __restrict__ W, const float* __restrict__ bias,
    float* __restrict__ xpT)
{
    __shared__ float AsT[32][132];
    __shared__ float Ws[32][132];
    __shared__ int toks[128];

    const int tid = threadIdx.x;
    const int mt = blockIdx.x / 24, nt = blockIdx.x % 24;
    const int m0 = mt * 128, n0 = nt * 128;

    if (tid < 128) {
        int mg = m0 + tid;
        toks[tid] = x[(mg & 63) * TT + (mg >> 6)];
    }
    __syncthreads();

    const int tx = tid & 15, ty = tid >> 4;
    float acc[8][8] = {};

    for (int kb = 0; kb < 8; ++kb) {
        const int k0 = kb * 32;
        if (kb) __syncthreads();
        #pragma unroll
        for (int i = 0; i < 4; ++i) {
            int idx = tid + 256 * i;
            int m = idx >> 3, c4 = idx & 7;
            float4 av = *(const float4*)(emb + (size_t)toks[m] * EE + k0 + c4 * 4);
            AsT[c4 * 4 + 0][m] = av.x; AsT[c4 * 4 + 1][m] = av.y;
            AsT[c4 * 4 + 2][m] = av.z; AsT[c4 * 4 + 3][m] = av.w;
            int r = idx >> 5, w4 = idx & 31;
            *(float4*)&Ws[r][w4 * 4] =
                *(const float4*)(W + (size_t)(k0 + r) * N3 + n0 + w4 * 4);
        }
        __syncthreads();
        #pragma unroll 8
        for (int kk = 0; kk < 32; ++kk) {
            float a8[8], w8[8];
            *(float4*)a8       = *(const float4*)&AsT[kk][ty * 8];
            *(float4*)(a8 + 4) = *(const float4*)&AsT[kk][ty * 8 + 4];
            *(float4*)w8       = *(const float4*)&Ws[kk][tx * 8];
            *(float4*)(w8 + 4) = *(const float4*)&Ws[kk][tx * 8 + 4];
            #pragma unroll
            for (int i = 0; i < 8; ++i)
                #pragma unroll
                for (int j = 0; j < 8; ++j) acc[i][j] += a8[i] * w8[j];
        }
    }

    float b8[8];
    *(float4*)b8       = *(const float4*)(bias + n0 + tx * 8);
    *(float4*)(b8 + 4) = *(const float4*)(bias + n0 + tx * 8 + 4);
    const int t0 = mt * 2 + (ty >> 3);
    const int bb0 = (ty & 7) * 8;
    #pragma unroll
    for (int j = 0; j < 8; ++j) {
        const int c = n0 + tx * 8 + j;
        float4 lo, hi;
        lo.x = acc[0][j] + b8[j]; lo.y = acc[1][j] + b8[j];
        lo.z = acc[2][j] + b8[j]; lo.w = acc[3][j] + b8[j];
        hi.x = acc[4][j] + b8[j]; hi.y = acc[5][j] + b8[j];
        hi.z = acc[6][j] + b8[j]; hi.w = acc[7][j] + b8[j];
        size_t base = ((size_t)t0 * N3 + c) * BB + bb0;
        *(float4*)(xpT + base)     = lo;
        *(float4*)(xpT + base + 4) = hi;
    }
}

// ---------------------------------------------------------------------------
// Kernel 2: persistent GRU scan, 64 blocks x 512 threads (coop launch).
//
// Coherence (unchanged from R6): h written via SYSTEM WT stores, read via
// SYSTEM relaxed atomic u64 loads (LLC-fresh, no buffer_inv). cnt via
// SYSTEM atomics. L1/L2 stay warm for xpT/xT/upack.
//
// Barrier restructured this round (per-wave arrive/poll):
//   - waves 4/5 arrive THEMSELVES after their h store-ack (waitcnt covers
//     only their 2 stores: deferred xpT stores moved after the B-loads at
//     step top). No tid0 agent, no pre-arrive or post-poll syncthreads.
//   - every wave polls the 8 group lines independently (all lanes same
//     address -> coalesced broadcast load) and proceeds straight to its
//     B-loads. Group target 16*(t+1) (2 arrivals per block, monotonic).
//   - poll is a BUSY spin with a dependent-FMA chain (no s_sleep): removes
//     sleep quantization from detect latency and raises VALUBusy (DVFS
//     probe: if the governor was downclocking an idle-looking kernel,
//     the clock comes up).
//   - per step now only 3 __syncthreads: red2, redS, hstage.
// ---------------------------------------------------------------------------
__global__ __launch_bounds__(512) void gru_persist(
    const int* __restrict__ xT, const float* __restrict__ upack,
    const float* __restrict__ bias, float* xpT,
    float* __restrict__ out, const float* __restrict__ hidden,
    unsigned short* hb0, unsigned short* hb1, unsigned* cnt)
{
    __shared__ f32x4 red2[6144];            // 96 KB: [q][gn][lane]
    __shared__ f32x4 redS[768];             // 12 KB: q-summed partials
    __shared__ unsigned short hstage[64 * 20]; // 2.5 KB: [b][du(16)+pad]

    const int tid = threadIdx.x;
    const int U0 = blockIdx.x * 16;
    const int w = tid >> 6;                 // wave: k-eighth
    const int lane = tid & 63;

    // gating identity: unit U0+gdu, batches gbA and gbA+32
    const int gdu = tid >> 5;               // 0..15
    const int gbA = tid & 31;               // 0..31

    // ---- prologue: A-fragments (U bf16) into registers, once ----
    bf16x8 af[3][4];
    {
        const int du = lane & 15;
        #pragma unroll
        for (int g = 0; g < 3; ++g)
            #pragma unroll
            for (int s = 0; s < 4; ++s) {
                const int k0 = w * 128 + s * 32 + (lane >> 4) * 8;
                const float* p = upack + (size_t)((U0 + du) * 3 + g) * NU + k0;
                float4 v0 = *(const float4*)p;
                float4 v1 = *(const float4*)(p + 4);
                af[g][s] = (bf16x8){ (short)f2bf(v0.x), (short)f2bf(v0.y),
                                     (short)f2bf(v0.z), (short)f2bf(v0.w),
                                     (short)f2bf(v1.x), (short)f2bf(v1.y),
                                     (short)f2bf(v1.z), (short)f2bf(v1.w) };
            }
    }

    float holdA = hidden[(size_t)gbA * NU + U0 + gdu];
    float holdB = hidden[(size_t)(gbA + 32) * NU + U0 + gdu];
    const float brz = bias[N3 + 0 * NU + U0 + gdu];
    const float brr = bias[N3 + 1 * NU + U0 + gdu];
    const float brh = bias[N3 + 2 * NU + U0 + gdu];
    float xzA, xrA, xhA, xzB, xrB, xhB; int tokA, tokB;
    {
        size_t xb = ((size_t)0 * N3 + U0 + gdu) * BB + gbA;
        xzA = xpT[xb];                      xzB = xpT[xb + 32];
        xrA = xpT[xb + (size_t)NU * BB];    xrB = xpT[xb + (size_t)NU * BB + 32];
        xhA = xpT[xb + (size_t)2 * NU * BB];xhB = xpT[xb + (size_t)2 * NU * BB + 32];
        tokA = xT[0 * BB + gbA];            tokB = xT[0 * BB + gbA + 32];
    }
    float* state_out = out + (size_t)BB * TT * NU;
    __syncthreads();

    const unsigned short* hc = hb0;
    unsigned short* hn = hb1;

    for (int t = 0; t < TT; ++t) {
        // ---- B-fragments FIRST (critical path): SYSTEM atomic u64 loads ----
        bf16x8 bv[4][4];
        #pragma unroll
        for (int n = 0; n < 4; ++n)
            #pragma unroll
            for (int s = 0; s < 4; ++s) {
                const int ew = w * 16 + s * 4 + (lane >> 4);
                const unsigned long long* hq = (const unsigned long long*)(hc +
                    (size_t)(ew * 64 + n * 16 + (lane & 15)) * 8);
                union { unsigned long long q[2]; bf16x8 v; } uu;
                uu.q[0] = __hip_atomic_load(hq, __ATOMIC_RELAXED,
                                            __HIP_MEMORY_SCOPE_SYSTEM);
                uu.q[1] = __hip_atomic_load(hq + 1, __ATOMIC_RELAXED,
                                            __HIP_MEMORY_SCOPE_SYSTEM);
                bv[n][s] = uu.v;
            }

        // ---- deferred output stores for step t-1 (issued AFTER the loads;
        //      fire-and-forget, drain during this step's compute) ----
        if (t > 0) {
            size_t ob = ((size_t)(t - 1) * N3 + U0 + gdu) * BB + gbA;
            __hip_atomic_store(&xpT[ob], holdA,
                               __ATOMIC_RELAXED, __HIP_MEMORY_SCOPE_SYSTEM);
            __hip_atomic_store(&xpT[ob + 32], holdB,
                               __ATOMIC_RELAXED, __HIP_MEMORY_SCOPE_SYSTEM);
        }

        // ---- MFMA: 3 gate-tiles x 4 batch-tiles, K=128 per wave ----
        f32x4 c[3][4];
        #pragma unroll
        for (int g = 0; g < 3; ++g)
            #pragma unroll
            for (int n = 0; n < 4; ++n) c[g][n] = (f32x4){0.f, 0.f, 0.f, 0.f};
        #pragma unroll
        for (int s = 0; s < 4; ++s)
            #pragma unroll
            for (int g = 0; g < 3; ++g)
                #pragma unroll
                for (int n = 0; n < 4; ++n)
                    c[g][n] = __builtin_amdgcn_mfma_f32_16x16x32_bf16(
                        af[g][s], bv[n][s], c[g][n], 0, 0, 0);

        #pragma unroll
        for (int g = 0; g < 3; ++g)
            #pragma unroll
            for (int n = 0; n < 4; ++n)
                red2[(w * 12 + g * 4 + n) * 64 + lane] = c[g][n];
        __syncthreads();

        // ---- pass1: q-sum, conflict-free consecutive b128 reads ----
        {
            f32x4 s0 = red2[tid];
            #pragma unroll
            for (int q = 1; q < 8; ++q) s0 += red2[q * 768 + tid];
            redS[tid] = s0;
            if (tid < 256) {
                const int o2 = 512 + tid;
                f32x4 s1 = red2[o2];
                #pragma unroll
                for (int q = 1; q < 8; ++q) s1 += red2[q * 768 + o2];
                redS[o2] = s1;
            }
        }
        __syncthreads();

        // ---- gating: unit U0+gdu, batches gbA and gbA+32 (6 LDS reads) ----
        {
            const int lA = (gdu >> 2) * 16 + (gbA & 15);
            const int rsub = gdu & 3;
            const int nA = gbA >> 4;        // 0 or 1; batch+32 -> nA+2
            float rzA = brz + ((const float*)&redS[(0 * 4 + nA) * 64 + lA])[rsub];
            float rrA = brr + ((const float*)&redS[(1 * 4 + nA) * 64 + lA])[rsub];
            float rhA = brh + ((const float*)&redS[(2 * 4 + nA) * 64 + lA])[rsub];
            float rzB = brz + ((const float*)&redS[(0 * 4 + nA + 2) * 64 + lA])[rsub];
            float rrB = brr + ((const float*)&redS[(1 * 4 + nA + 2) * 64 + lA])[rsub];
            float rhB = brh + ((const float*)&redS[(2 * 4 + nA + 2) * 64 + lA])[rsub];

            float zA  = 1.f / (1.f + expf(-(xzA + rzA)));
            float rA  = 1.f / (1.f + expf(-(xrA + rrA)));
            float hhA = tanhf(xhA + rA * rhA);
            float hnewA = zA * holdA + (1.f - zA) * hhA;
            if (tokA == 0) hnewA = holdA;
            float zB  = 1.f / (1.f + expf(-(xzB + rzB)));
            float rB  = 1.f / (1.f + expf(-(xrB + rrB)));
            float hhB = tanhf(xhB + rB * rhB);
            float hnewB = zB * holdB + (1.f - zB) * hhB;
            if (tokB == 0) hnewB = holdB;

            hstage[gbA * 20 + gdu] = f2bf(hnewA);
            hstage[(gbA + 32) * 20 + gdu] = f2bf(hnewB);
            holdA = hnewA; holdB = hnewB;   // deferred store next iter
        }
        __syncthreads();

        // ---- h_bf store + ARRIVE (waves 4,5 only; own stores drained) ----
        if (w == 4 || w == 5) {
            const int g2 = w - 4;
            unsigned long long lo =
                *(const unsigned long long*)&hstage[lane * 20 + 8 * g2];
            unsigned long long hi =
                *(const unsigned long long*)&hstage[lane * 20 + 8 * g2 + 4];
            unsigned short* dst = hn + ((size_t)((U0 >> 3) + g2) * 64 + lane) * 8;
            __hip_atomic_store((unsigned long long*)dst, lo,
                               __ATOMIC_RELAXED, __HIP_MEMORY_SCOPE_SYSTEM);
            __hip_atomic_store((unsigned long long*)(dst + 4), hi,
                               __ATOMIC_RELAXED, __HIP_MEMORY_SCOPE_SYSTEM);
            __builtin_amdgcn_s_waitcnt(0);  // ack: only these 2 stores left
            if (lane == 0)
                __hip_atomic_fetch_add(&cnt[((unsigned)blockIdx.x >> 3) * 32], 1u,
                                       __ATOMIC_RELAXED, __HIP_MEMORY_SCOPE_SYSTEM);
        }

        // ---- prefetch t+1 gating inputs (overlaps the poll) ----
        if (t + 1 < TT) {
            size_t xb = ((size_t)(t + 1) * N3 + U0 + gdu) * BB + gbA;
            xzA = xpT[xb];                      xzB = xpT[xb + 32];
            xrA = xpT[xb + (size_t)NU * BB];    xrB = xpT[xb + (size_t)NU * BB + 32];
            xhA = xpT[xb + (size_t)2 * NU * BB];xhB = xpT[xb + (size_t)2 * NU * BB + 32];
            tokA = xT[(t + 1) * BB + gbA];      tokB = xT[(t + 1) * BB + gbA + 32];
        }

        // ---- per-wave busy poll: all lanes, same addrs (bcast loads) ----
        {
            const unsigned tgt = 16u * ((unsigned)t + 1u);
            unsigned mn;
            long guard = 0;
            float dummy = (float)t;
            do {
                mn = 0xffffffffu;
                #pragma unroll
                for (int g8 = 0; g8 < 8; ++g8) {
                    unsigned v = __hip_atomic_load(&cnt[g8 * 32],
                                  __ATOMIC_RELAXED, __HIP_MEMORY_SCOPE_SYSTEM);
                    mn = v < mn ? v : mn;
                }
                #pragma unroll
                for (int d = 0; d < 16; ++d)
                    dummy = fmaf(dummy, 1.0000001f, 1e-30f);
            } while (mn < tgt && ++guard < (1L << 24));
            if (guard >= (1L << 24)) redS[0].x += dummy;  // never; keeps dummy live
        }
        // no syncthreads: each wave proceeds to its own B-loads; target
        // reached implies ALL blocks' h(t) stores are LLC-visible.

        const unsigned short* tmp = hc; hc = hn; hn = (unsigned short*)tmp;
    }

    // ---- final deferred stores: out slice TT-1 + state ----
    {
        size_t ob = ((size_t)(TT - 1) * N3 + U0 + gdu) * BB + gbA;
        __hip_atomic_store(&xpT[ob], holdA,
                           __ATOMIC_RELAXED, __HIP_MEMORY_SCOPE_SYSTEM);
        __hip_atomic_store(&xpT[ob + 32], holdB,
                           __ATOMIC_RELAXED, __HIP_MEMORY_SCOPE_SYSTEM);
        __hip_atomic_store(&state_out[(size_t)gbA * NU + U0 + gdu], holdA,
                           __ATOMIC_RELAXED, __HIP_MEMORY_SCOPE_SYSTEM);
        __hip_atomic_store(&state_out[(size_t)(gbA + 32) * NU + U0 + gdu], holdB,
                           __ATOMIC_RELAXED, __HIP_MEMORY_SCOPE_SYSTEM);
    }
}

// ---------------------------------------------------------------------------
// Kernel 3: transpose per-step outputs from xpT's xz slices [T][U][B]
// into out [B][T][U].  (unchanged)
// ---------------------------------------------------------------------------
__global__ __launch_bounds__(256) void outT_kernel(
    const float* __restrict__ xpT, float* __restrict__ out)
{
    __shared__ float tile[64][65];
    const int t = blockIdx.x, u0 = blockIdx.y * 64;
    const int lane = threadIdx.x & 63, row = threadIdx.x >> 6;
    #pragma unroll
    for (int r = row; r < 64; r += 4)
        tile[r][lane] = xpT[((size_t)t * N3 + u0 + r) * BB + lane];
    __syncthreads();
    #pragma unroll
    for (int b = row; b < 64; b += 4)
        out[((size_t)b * TT + t) * NU + u0 + lane] = tile[lane][b];
}

// ---------------------------------------------------------------------------
extern "C" void kernel_launch(void* const* d_in, const int* in_sizes, int n_in,
                              void* d_out, int out_size, void* d_ws, size_t ws_size,
                              hipStream_t stream) {
    const int*   x      = (const int*)d_in[0];
    const float* hidden = (const float*)d_in[1];
    const float* emb    = (const float*)d_in[2];
    const float* W      = (const float*)d_in[3];
    const float* U      = (const float*)d_in[4];
    const float* bvec   = (const float*)d_in[5];

    float* out = (float*)d_out;

    float*          xpT   = (float*)d_ws;                     // 50,331,648 f
    float*          upck  = xpT + (size_t)16384 * N3;         //  3,145,728 f
    unsigned short* hb0   = (unsigned short*)(upck + (size_t)3 * NU * NU);
    unsigned short* hb1   = hb0 + (size_t)NU * BB;            // 65,536 u16 ea
    int*            xT    = (int*)(hb1 + (size_t)NU * BB);    // 16,384 ints
    unsigned*       cnt   = (unsigned*)(xT + TT * BB);        // 512 uints

    upack_kernel<<<dim3(96, 32), dim3(256), 0, stream>>>(U, upck);
    tokT_kernel<<<dim3(TT), dim3(64), 0, stream>>>(x, xT);
    hinit_kernel<<<dim3(256), dim3(256), 0, stream>>>(hidden, hb0, cnt);
    xprojT_kernel<<<dim3(3072), dim3(256), 0, stream>>>(x, emb, W, bvec, xpT);

    void* args[] = {(void*)&xT, (void*)&upck, (void*)&bvec, (void*)&xpT,
                    (void*)&out, (void*)&hidden, (void*)&hb0, (void*)&hb1,
                    (void*)&cnt};
    hipLaunchCooperativeKernel((const void*)gru_persist, dim3(64), dim3(512),
                               args, 0, stream);

    outT_kernel<<<dim3(TT, 16), dim3(256), 0, stream>>>(xpT, out);
}

// Round 8
// 1993.373 us; speedup vs baseline: 1.0900x; 1.0900x over previous
//
#include <hip/hip_runtime.h>
#include <hip/hip_cooperative_groups.h>

#define BB 64      // batch
#define TT 256     // time
#define EE 256     // embed dim
#define NU 1024    // hidden units
#define N3 3072    // 3*NU

typedef __attribute__((ext_vector_type(8))) short bf16x8;
typedef __attribute__((ext_vector_type(4))) float f32x4;

__device__ __forceinline__ unsigned short f2bf(float f) {
    unsigned u = __float_as_uint(f);
    return (unsigned short)((u + 0x7FFFu + ((u >> 16) & 1u)) >> 16);
}

__device__ __forceinline__ unsigned long long packf2(float a, float b) {
    return (unsigned long long)__float_as_uint(a) |
           ((unsigned long long)__float_as_uint(b) << 32);
}

// ---------------------------------------------------------------------------
// Kernel 0a: pack U[k][g*NU+u] -> Upack[u*3+g][k]  (fp32, unchanged)
// ---------------------------------------------------------------------------
__global__ __launch_bounds__(256) void upack_kernel(
    const float* __restrict__ U, float* __restrict__ up)
{
    __shared__ float t32[32][33];
    const int c0 = blockIdx.x * 32, k0 = blockIdx.y * 32;
    const int tx = threadIdx.x & 31, ty = threadIdx.x >> 5;
    #pragma unroll
    for (int i = 0; i < 4; ++i) {
        int k = ty + i * 8;
        t32[k][tx] = U[(size_t)(k0 + k) * N3 + c0 + tx];
    }
    __syncthreads();
    #pragma unroll
    for (int i = 0; i < 4; ++i) {
        int cl = ty + i * 8;
        int c = c0 + cl;
        int u = c & 1023, g = c >> 10;
        up[(size_t)(u * 3 + g) * NU + k0 + tx] = t32[tx][cl];
    }
}

// ---------------------------------------------------------------------------
// Kernel 0b: transpose tokens; 0c: init h_bf16 (frag layout) + zero counters
// h_bf layout: elem((k,b)) = ((k>>3)*64 + b)*8 + (k&7)
// ---------------------------------------------------------------------------
__global__ __launch_bounds__(64) void tokT_kernel(
    const int* __restrict__ x, int* __restrict__ xT)
{
    const int t = blockIdx.x, b = threadIdx.x;
    xT[t * BB + b] = x[b * TT + t];
}

__global__ __launch_bounds__(256) void hinit_kernel(
    const float* __restrict__ hidden, unsigned short* __restrict__ hb0,
    unsigned* __restrict__ cnt)
{
    const int u = blockIdx.x * 4 + (threadIdx.x >> 6);
    const int b = threadIdx.x & 63;
    hb0[((u >> 3) * 64 + b) * 8 + (u & 7)] = f2bf(hidden[(size_t)b * NU + u]);
    if (blockIdx.x == 0) {
        cnt[threadIdx.x] = 0u;           // group counters (8 x 32-uint pad)
        cnt[threadIdx.x + 256] = 0u;     // incl. ready[] at cnt[320..447]
    }
}

// ---------------------------------------------------------------------------
// Fused persistent kernel: 256 blocks x 512 threads (coop launch, 1 blk/CU).
//   blocks 0-63  : GRU scan (R6 structure: WT h stores, system-atomic h
//                  loads, tid0 tree barrier + sleep poll, NO buffer_inv)
//   blocks 64-255: xprojT producer tiles (mt-major, WT stores, ready[mt]
//                  counters), then dependent-FMA burn until the scan ends
//                  (keeps 192 CUs busy -> DVFS stays up; also absorbs the
//                  ~330us xprojT kernel into the scan's first steps)
// GRU output goes DIRECTLY to out[b][t][u] (plain deferred stores) ->
// outT kernel eliminated.
// ---------------------------------------------------------------------------
__global__ __launch_bounds__(512) void gru_persist(
    const int* __restrict__ xT, const float* __restrict__ upack,
    const float* __restrict__ bias, float* xpT,
    float* __restrict__ out, const float* __restrict__ hidden,
    unsigned short* hb0, unsigned short* hb1, unsigned* cnt,
    const int* __restrict__ x, const float* __restrict__ emb,
    const float* __restrict__ W)
{
    __shared__ f32x4 red2[6144];            // 96 KB: [q][gn][lane] / worker LDS
    __shared__ f32x4 redS[768];             // 12 KB: q-summed partials
    __shared__ unsigned short hstage[64 * 20]; // 2.5 KB

    const int tid = threadIdx.x;
    unsigned* rdy = cnt + 320;              // ready[mt], mt<128, 24 tiles each

    // =======================================================================
    // Worker path: xprojT tiles, then burn
    // =======================================================================
    if (blockIdx.x >= 64) {
        const int wid = blockIdx.x - 64;    // 0..191
        float* AsT = (float*)red2;          // [32][132] floats
        float* Ws  = (float*)red2 + 4224;   // [32][132]
        int*  toks = (int*)((float*)red2 + 8448);  // [128]
        const int tx = tid & 15, ty2 = tid >> 4;   // ty2: 0..31

        for (int idx0 = wid; idx0 < 3072; idx0 += 192) {
            const int mt = idx0 / 24, nt = idx0 % 24;
            const int m0 = mt * 128, n0 = nt * 128;

            if (tid < 128) {
                int mg = m0 + tid;
                toks[tid] = x[(mg & 63) * TT + (mg >> 6)];
            }
            __syncthreads();

            float acc[4][8] = {};
            for (int kb = 0; kb < 8; ++kb) {
                const int k0 = kb * 32;
                if (kb) __syncthreads();
                #pragma unroll
                for (int i = 0; i < 2; ++i) {
                    int idx = tid + 512 * i;            // 0..1023
                    int m = idx >> 3, c4 = idx & 7;
                    float4 av = *(const float4*)(emb +
                        (size_t)toks[m] * EE + k0 + c4 * 4);
                    AsT[(c4 * 4 + 0) * 132 + m] = av.x;
                    AsT[(c4 * 4 + 1) * 132 + m] = av.y;
                    AsT[(c4 * 4 + 2) * 132 + m] = av.z;
                    AsT[(c4 * 4 + 3) * 132 + m] = av.w;
                    int r = idx >> 5, w4 = idx & 31;
                    *(float4*)&Ws[r * 132 + w4 * 4] =
                        *(const float4*)(W + (size_t)(k0 + r) * N3 + n0 + w4 * 4);
                }
                __syncthreads();
                #pragma unroll 8
                for (int kk = 0; kk < 32; ++kk) {
                    float a4[4], w8[8];
                    *(float4*)a4       = *(const float4*)&AsT[kk * 132 + ty2 * 4];
                    *(float4*)w8       = *(const float4*)&Ws[kk * 132 + tx * 8];
                    *(float4*)(w8 + 4) = *(const float4*)&Ws[kk * 132 + tx * 8 + 4];
                    #pragma unroll
                    for (int i = 0; i < 4; ++i)
                        #pragma unroll
                        for (int j = 0; j < 8; ++j) acc[i][j] += a4[i] * w8[j];
                }
            }

            float b8[8];
            *(float4*)b8       = *(const float4*)(bias + n0 + tx * 8);
            *(float4*)(b8 + 4) = *(const float4*)(bias + n0 + tx * 8 + 4);
            const int t0 = mt * 2 + (ty2 >> 4);
            const int bq0 = (ty2 & 15) * 4;
            #pragma unroll
            for (int j = 0; j < 8; ++j) {
                const int c = n0 + tx * 8 + j;
                float f0 = acc[0][j] + b8[j], f1 = acc[1][j] + b8[j];
                float f2 = acc[2][j] + b8[j], f3 = acc[3][j] + b8[j];
                size_t base = ((size_t)t0 * N3 + c) * BB + bq0;
                __hip_atomic_store((unsigned long long*)(xpT + base),
                                   packf2(f0, f1),
                                   __ATOMIC_RELAXED, __HIP_MEMORY_SCOPE_SYSTEM);
                __hip_atomic_store((unsigned long long*)(xpT + base + 2),
                                   packf2(f2, f3),
                                   __ATOMIC_RELAXED, __HIP_MEMORY_SCOPE_SYSTEM);
            }
            __builtin_amdgcn_s_waitcnt(0);          // WT stores LLC-visible
            __syncthreads();
            if (tid == 0)
                __hip_atomic_fetch_add(&rdy[mt], 1u,
                                       __ATOMIC_RELAXED, __HIP_MEMORY_SCOPE_SYSTEM);
            __syncthreads();
        }

        // ---- DVFS burn: real VALU load until the scan completes ----
        {
            float d0 = 1.0f + tid * 1e-7f, d1 = 1.1f, d2 = 1.2f, d3 = 1.3f;
            long guard = 0;
            for (;;) {
                unsigned mn = 0xffffffffu;
                #pragma unroll
                for (int g8 = 0; g8 < 8; ++g8) {
                    unsigned v = __hip_atomic_load(&cnt[g8 * 32],
                                  __ATOMIC_RELAXED, __HIP_MEMORY_SCOPE_SYSTEM);
                    mn = v < mn ? v : mn;
                }
                if (mn >= 8u * TT || ++guard > (1L << 22)) break;
                #pragma unroll
                for (int d = 0; d < 256; ++d) {
                    d0 = fmaf(d0, 1.0000001f, 1e-30f);
                    d1 = fmaf(d1, 0.9999999f, 1e-30f);
                    d2 = fmaf(d2, 1.0000002f, -1e-30f);
                    d3 = fmaf(d3, 0.9999998f, -1e-30f);
                }
            }
            asm volatile("" :: "v"(d0), "v"(d1), "v"(d2), "v"(d3));
        }
        return;
    }

    // =======================================================================
    // GRU path (R6 structure; blocks 0-63)
    // =======================================================================
    const int U0 = blockIdx.x * 16;
    const int w = tid >> 6;                 // wave: k-eighth
    const int lane = tid & 63;
    const int gdu = tid >> 5;               // 0..15 : unit offset
    const int gbA = tid & 31;               // 0..31 : batch (and +32)

    // ---- prologue: A-fragments (U bf16) into registers, once ----
    bf16x8 af[3][4];
    {
        const int du = lane & 15;
        #pragma unroll
        for (int g = 0; g < 3; ++g)
            #pragma unroll
            for (int s = 0; s < 4; ++s) {
                const int k0 = w * 128 + s * 32 + (lane >> 4) * 8;
                const float* p = upack + (size_t)((U0 + du) * 3 + g) * NU + k0;
                float4 v0 = *(const float4*)p;
                float4 v1 = *(const float4*)(p + 4);
                af[g][s] = (bf16x8){ (short)f2bf(v0.x), (short)f2bf(v0.y),
                                     (short)f2bf(v0.z), (short)f2bf(v0.w),
                                     (short)f2bf(v1.x), (short)f2bf(v1.y),
                                     (short)f2bf(v1.z), (short)f2bf(v1.w) };
            }
    }

    float holdA = hidden[(size_t)gbA * NU + U0 + gdu];
    float holdB = hidden[(size_t)(gbA + 32) * NU + U0 + gdu];
    const float brz = bias[N3 + 0 * NU + U0 + gdu];
    const float brr = bias[N3 + 1 * NU + U0 + gdu];
    const float brh = bias[N3 + 2 * NU + U0 + gdu];

    // wait for xproj time-slice 0, then load t=0 gating inputs
    {
        unsigned r; long guard = 0;
        do {
            r = __hip_atomic_load(&rdy[0], __ATOMIC_RELAXED,
                                  __HIP_MEMORY_SCOPE_SYSTEM);
            if (r < 24u) __builtin_amdgcn_s_sleep(1);
        } while (r < 24u && ++guard < (1L << 24));
    }
    float xzA, xrA, xhA, xzB, xrB, xhB; int tokA, tokB;
    {
        size_t xb = ((size_t)0 * N3 + U0 + gdu) * BB + gbA;
        xzA = xpT[xb];                      xzB = xpT[xb + 32];
        xrA = xpT[xb + (size_t)NU * BB];    xrB = xpT[xb + (size_t)NU * BB + 32];
        xhA = xpT[xb + (size_t)2 * NU * BB];xhB = xpT[xb + (size_t)2 * NU * BB + 32];
        tokA = xT[0 * BB + gbA];            tokB = xT[0 * BB + gbA + 32];
    }
    float* state_out = out + (size_t)BB * TT * NU;
    __syncthreads();

    const unsigned short* hc = hb0;
    unsigned short* hn = hb1;

    for (int t = 0; t < TT; ++t) {
        // ---- deferred DIRECT out stores for step t-1 (plain, scattered,
        //      fire-and-forget; drain during this step's compute) ----
        if (t > 0) {
            out[((size_t)gbA * TT + (t - 1)) * NU + U0 + gdu] = holdA;
            out[((size_t)(gbA + 32) * TT + (t - 1)) * NU + U0 + gdu] = holdB;
        }

        // ---- B-fragments: SYSTEM atomic u64 loads (LLC-fresh, no inv) ----
        bf16x8 bv[4][4];
        #pragma unroll
        for (int n = 0; n < 4; ++n)
            #pragma unroll
            for (int s = 0; s < 4; ++s) {
                const int ew = w * 16 + s * 4 + (lane >> 4);
                const unsigned long long* hq = (const unsigned long long*)(hc +
                    (size_t)(ew * 64 + n * 16 + (lane & 15)) * 8);
                union { unsigned long long q[2]; bf16x8 v; } uu;
                uu.q[0] = __hip_atomic_load(hq, __ATOMIC_RELAXED,
                                            __HIP_MEMORY_SCOPE_SYSTEM);
                uu.q[1] = __hip_atomic_load(hq + 1, __ATOMIC_RELAXED,
                                            __HIP_MEMORY_SCOPE_SYSTEM);
                bv[n][s] = uu.v;
            }

        // ---- MFMA: 3 gate-tiles x 4 batch-tiles, K=128 per wave ----
        f32x4 c[3][4];
        #pragma unroll
        for (int g = 0; g < 3; ++g)
            #pragma unroll
            for (int n = 0; n < 4; ++n) c[g][n] = (f32x4){0.f, 0.f, 0.f, 0.f};
        #pragma unroll
        for (int s = 0; s < 4; ++s)
            #pragma unroll
            for (int g = 0; g < 3; ++g)
                #pragma unroll
                for (int n = 0; n < 4; ++n)
                    c[g][n] = __builtin_amdgcn_mfma_f32_16x16x32_bf16(
                        af[g][s], bv[n][s], c[g][n], 0, 0, 0);

        #pragma unroll
        for (int g = 0; g < 3; ++g)
            #pragma unroll
            for (int n = 0; n < 4; ++n)
                red2[(w * 12 + g * 4 + n) * 64 + lane] = c[g][n];
        __syncthreads();

        // ---- pass1: q-sum, conflict-free consecutive b128 reads ----
        {
            f32x4 s0 = red2[tid];
            #pragma unroll
            for (int q = 1; q < 8; ++q) s0 += red2[q * 768 + tid];
            redS[tid] = s0;
            if (tid < 256) {
                const int o2 = 512 + tid;
                f32x4 s1 = red2[o2];
                #pragma unroll
                for (int q = 1; q < 8; ++q) s1 += red2[q * 768 + o2];
                redS[o2] = s1;
            }
        }
        __syncthreads();

        // ---- gating: unit U0+gdu, batches gbA and gbA+32 (6 LDS reads) ----
        {
            const int lA = (gdu >> 2) * 16 + (gbA & 15);
            const int rsub = gdu & 3;
            const int nA = gbA >> 4;        // 0 or 1; batch+32 -> nA+2
            float rzA = brz + ((const float*)&redS[(0 * 4 + nA) * 64 + lA])[rsub];
            float rrA = brr + ((const float*)&redS[(1 * 4 + nA) * 64 + lA])[rsub];
            float rhA = brh + ((const float*)&redS[(2 * 4 + nA) * 64 + lA])[rsub];
            float rzB = brz + ((const float*)&redS[(0 * 4 + nA + 2) * 64 + lA])[rsub];
            float rrB = brr + ((const float*)&redS[(1 * 4 + nA + 2) * 64 + lA])[rsub];
            float rhB = brh + ((const float*)&redS[(2 * 4 + nA + 2) * 64 + lA])[rsub];

            float zA  = 1.f / (1.f + expf(-(xzA + rzA)));
            float rA  = 1.f / (1.f + expf(-(xrA + rrA)));
            float hhA = tanhf(xhA + rA * rhA);
            float hnewA = zA * holdA + (1.f - zA) * hhA;
            if (tokA == 0) hnewA = holdA;
            float zB  = 1.f / (1.f + expf(-(xzB + rzB)));
            float rB  = 1.f / (1.f + expf(-(xrB + rrB)));
            float hhB = tanhf(xhB + rB * rhB);
            float hnewB = zB * holdB + (1.f - zB) * hhB;
            if (tokB == 0) hnewB = holdB;

            hstage[gbA * 20 + gdu] = f2bf(hnewA);
            hstage[(gbA + 32) * 20 + gdu] = f2bf(hnewB);
            holdA = hnewA; holdB = hnewB;   // deferred out store next iter
        }
        __syncthreads();

        // ---- h_bf store: waves 4,5 pack 8 units x 64 batches each (WT) ----
        if (w == 4 || w == 5) {
            const int g2 = w - 4;
            unsigned long long lo =
                *(const unsigned long long*)&hstage[lane * 20 + 8 * g2];
            unsigned long long hi =
                *(const unsigned long long*)&hstage[lane * 20 + 8 * g2 + 4];
            unsigned short* dst = hn + ((size_t)((U0 >> 3) + g2) * 64 + lane) * 8;
            __hip_atomic_store((unsigned long long*)dst, lo,
                               __ATOMIC_RELAXED, __HIP_MEMORY_SCOPE_SYSTEM);
            __hip_atomic_store((unsigned long long*)(dst + 4), hi,
                               __ATOMIC_RELAXED, __HIP_MEMORY_SCOPE_SYSTEM);
        }

        // ---- barrier: drain stores, arrive (tid0), sleep-poll 8 lines ----
        __builtin_amdgcn_s_waitcnt(0);
        __syncthreads();

        // ready-poll + prefetch t+1 gating inputs (overlaps the barrier)
        if (t + 1 < TT) {
            const int mtp = (t + 1) >> 1;
            unsigned r; long guard = 0;
            do {
                r = __hip_atomic_load(&rdy[mtp], __ATOMIC_RELAXED,
                                      __HIP_MEMORY_SCOPE_SYSTEM);
                if (r < 24u) __builtin_amdgcn_s_sleep(1);
            } while (r < 24u && ++guard < (1L << 24));
            size_t xb = ((size_t)(t + 1) * N3 + U0 + gdu) * BB + gbA;
            xzA = xpT[xb];                      xzB = xpT[xb + 32];
            xrA = xpT[xb + (size_t)NU * BB];    xrB = xpT[xb + (size_t)NU * BB + 32];
            xhA = xpT[xb + (size_t)2 * NU * BB];xhB = xpT[xb + (size_t)2 * NU * BB + 32];
            tokA = xT[(t + 1) * BB + gbA];      tokB = xT[(t + 1) * BB + gbA + 32];
        }

        if (tid == 0) {
            const unsigned g = (unsigned)blockIdx.x >> 3;   // 8 groups x 8
            __hip_atomic_fetch_add(&cnt[g * 32], 1u,
                                   __ATOMIC_RELAXED, __HIP_MEMORY_SCOPE_SYSTEM);
            const unsigned tgt = 8u * ((unsigned)t + 1u);
            unsigned mn;
            long guard = 0;
            do {
                mn = 0xffffffffu;
                #pragma unroll
                for (int g8 = 0; g8 < 8; ++g8) {
                    unsigned v = __hip_atomic_load(&cnt[g8 * 32],
                                  __ATOMIC_RELAXED, __HIP_MEMORY_SCOPE_SYSTEM);
                    mn = v < mn ? v : mn;
                }
                if (mn < tgt) __builtin_amdgcn_s_sleep(1);
            } while (mn < tgt && ++guard < (1L << 24));
        }
        __syncthreads();

        const unsigned short* tmp = hc; hc = hn; hn = (unsigned short*)tmp;
    }

    // ---- final stores: out slice TT-1 + state (plain; kernel-end flush) ----
    {
        out[((size_t)gbA * TT + (TT - 1)) * NU + U0 + gdu] = holdA;
        out[((size_t)(gbA + 32) * TT + (TT - 1)) * NU + U0 + gdu] = holdB;
        state_out[(size_t)gbA * NU + U0 + gdu] = holdA;
        state_out[(size_t)(gbA + 32) * NU + U0 + gdu] = holdB;
    }
}

// ---------------------------------------------------------------------------
extern "C" void kernel_launch(void* const* d_in, const int* in_sizes, int n_in,
                              void* d_out, int out_size, void* d_ws, size_t ws_size,
                              hipStream_t stream) {
    const int*   x      = (const int*)d_in[0];
    const float* hidden = (const float*)d_in[1];
    const float* emb    = (const float*)d_in[2];
    const float* W      = (const float*)d_in[3];
    const float* U      = (const float*)d_in[4];
    const float* bvec   = (const float*)d_in[5];

    float* out = (float*)d_out;

    float*          xpT   = (float*)d_ws;                     // 50,331,648 f
    float*          upck  = xpT + (size_t)16384 * N3;         //  3,145,728 f
    unsigned short* hb0   = (unsigned short*)(upck + (size_t)3 * NU * NU);
    unsigned short* hb1   = hb0 + (size_t)NU * BB;            // 65,536 u16 ea
    int*            xT    = (int*)(hb1 + (size_t)NU * BB);    // 16,384 ints
    unsigned*       cnt   = (unsigned*)(xT + TT * BB);        // 512 uints

    upack_kernel<<<dim3(96, 32), dim3(256), 0, stream>>>(U, upck);
    tokT_kernel<<<dim3(TT), dim3(64), 0, stream>>>(x, xT);
    hinit_kernel<<<dim3(256), dim3(256), 0, stream>>>(hidden, hb0, cnt);

    void* args[] = {(void*)&xT, (void*)&upck, (void*)&bvec, (void*)&xpT,
                    (void*)&out, (void*)&hidden, (void*)&hb0, (void*)&hb1,
                    (void*)&cnt, (void*)&x, (void*)&emb, (void*)&W};
    hipLaunchCooperativeKernel((const void*)gru_persist, dim3(256), dim3(512),
                               args, 0, stream);
}